// Round 19
// baseline (1462.322 us; speedup 1.0000x reference)
//
#include <hip/hip_runtime.h>
#include <hip/hip_bf16.h>

#define T_TOK 12608      // 64*197
#define MPAD  12672      // 99*128
#define S_TOK 197
#define DEPTH_L 4

typedef __attribute__((ext_vector_type(8))) short short8;
typedef __attribute__((ext_vector_type(4))) short short4v;
typedef __attribute__((ext_vector_type(4))) float f32x4;

using gvoid = __attribute__((address_space(1))) const void;
using lvoid = __attribute__((address_space(3))) void;

__device__ __forceinline__ float gelu_f(float x) {
    return 0.5f * x * (1.f + erff(x * 0.70710678118654752440f));
}

__device__ __forceinline__ void split2(float v, __hip_bfloat16& h, __hip_bfloat16& l) {
    h = __float2bfloat16(v);
    l = __float2bfloat16(v - __bfloat162float(h));
}

// prefix base for expert e from counts (inline; no calc_base kernel)
__device__ __forceinline__ int base_of(const int* __restrict__ cnt, int e) {
    int b = 0;
#pragma unroll
    for (int k = 0; k < 3; ++k) if (e > k) b += cnt[k];
    return b;
}

// ---------------- split-bf16 3-product GEMM, 128x128 tile, BK=64 ----------------
// B stored as Bext[N][2K] = [Bhi | Blo] (no duplicated Bhi; -33% weight bytes).
// Per K-step (3 phases sharing one A buffer):
//   stage {Ahi, Bhi, Blo}; acc += Ahi*Bhi; acc += Ahi*Blo;
//   stage {Alo}->A buffer;  acc += Alo*Bhi
// = C ~ A*B with ~2^-16 rel error; per-product k-order identical to the old
// 3K-extension layout (only inter-product interleave differs: +-1 ulp).
// Barrier-pairs and LDS staging bytes per block: -33% vs 3K layout.
// XCD-interleaved swizzle: xcd=x&7, j=x>>3, p=(j%13)*8+xcd, c=j/13.
// LDS 3x16KB=48KB -> 3 blocks/CU; rule-21 XOR swizzle (col ^ ((row&7)<<4)).
// launch_bounds(256,4): PROVEN floor. (256,8)/(256,5) spill acc (r13/r16).
// MFMA kept as three separate 32-MFMA product blocks: 32 live frag regs each
// (acc 64 AGPR + ~60 VGPR <= 128 cap) — do NOT merge into one 3-operand loop.
// Split-K (MODE 3): blockIdx.y slice covers k in [y*kChunk,(y+1)*kChunk) of K;
// slice y plain-stores to outf + y*outStride; combine sums slices.
// MODE 0: outf = v + bias            (qkv)
// MODE 1: outf += v + bias           (attn out proj, residual)
// MODE 2: sparse moe1 (rowmap gather; gate*gelu; hi/lo out)
// MODE 3: sparse moe2 (compact A; plain store to slice buffer)
// MODE 4: patch embed scatter (+pos)
template<int MODE>
__global__ __launch_bounds__(256, 4)
void gemm3(const short* __restrict__ Ahi, const short* __restrict__ Alo, int ldA,
           const short* __restrict__ Bext,
           float* __restrict__ outf, __hip_bfloat16* __restrict__ outh, int ldOut,
           const float* __restrict__ bias, const float* __restrict__ gate,
           const float* __restrict__ aux,
           const int* __restrict__ rowmap, const int* __restrict__ cntp,
           int Mvalid, int N, int K, int npanels, int kChunk, size_t outStride)
{
    __shared__ short As[128 * 64];
    __shared__ short Bs0[128 * 64];
    __shared__ short Bs1[128 * 64];
    const int tid  = threadIdx.x;
    const int wid  = tid >> 6;
    const int lane = tid & 63;

    const int xcd = blockIdx.x & 7;
    const int j   = blockIdx.x >> 3;
    const int p   = (j % 13) * 8 + xcd;
    const int c   = j / 13;
    if (p >= npanels) return;            // uniform exit
    const int row0 = p * 128;
    const int col0 = c * 128;

    const int wr = (wid >> 1) * 64;
    const int wc = (wid & 1) * 64;
    const int e  = (MODE == 2 || MODE == 3) ? blockIdx.z : 0;

    int Mv = Mvalid;
    int baseRow = 0;
    const int* rmap = nullptr;
    if (MODE == 2 || MODE == 3) {
        Mv = cntp[e];
        if (row0 >= Mv) return;          // uniform early-exit (before any barrier)
        baseRow = base_of(cntp, e);
        if (MODE == 2) rmap = rowmap + e * T_TOK;
    }

    // MODE 2: row-indirect A staging; lane's tile row per i: (i*4+wid)*8+(lane>>3).
    int arow[4];
    if (MODE == 2) {
#pragma unroll
        for (int i = 0; i < 4; ++i) {
            int gr = row0 + (i * 4 + wid) * 8 + (lane >> 3);
            if (gr > Mv - 1) gr = Mv - 1;
            arow[i] = rmap[gr];
        }
    }

    f32x4 acc[4][4];
#pragma unroll
    for (int m = 0; m < 4; ++m)
#pragma unroll
        for (int n = 0; n < 4; ++n) acc[m][n] = (f32x4){0.f, 0.f, 0.f, 0.f};

    const int ld2 = 2 * K;
    const size_t strideA = (size_t)ldA * 2;
    const size_t strideB = (size_t)ld2 * 2;
    const char* Bbase = (const char*)Bext + ((size_t)e * N + col0) * strideB;

    const int kBeg = blockIdx.y * kChunk;
    int kEnd = kBeg + kChunk; if (kEnd > K) kEnd = K;

    const int lr = lane & 15;
    const int kbB = (lane >> 4) * 16;                        // frag byte offset within 64B

    for (int k0 = kBeg; k0 < kEnd; k0 += 64) {
        // ---- phase 1: stage Ahi, Bhi, Blo ----
        __syncthreads();
#pragma unroll
        for (int i = 0; i < 4; ++i) {
            const int chunk = (i * 4 + wid) * 1024;          // wave-uniform LDS dest (bytes)
            const int off = chunk + lane * 16;
            const int r = off >> 7;                          // 128B per tile row
            const int cb = off & 127;
            const int cbs = cb ^ ((r & 7) << 4);             // inverse-swizzled source col
            const char* asrc;
            if (MODE == 2) {
                asrc = (const char*)Ahi + (size_t)arow[i] * strideA + (size_t)k0 * 2 + cbs;
            } else {
                asrc = (const char*)Ahi + (size_t)(baseRow + row0 + r) * strideA + (size_t)k0 * 2 + cbs;
            }
            __builtin_amdgcn_global_load_lds((gvoid*)asrc, (lvoid*)((char*)As + chunk), 16, 0, 0);
            __builtin_amdgcn_global_load_lds(
                (gvoid*)(Bbase + (size_t)r * strideB + (size_t)k0 * 2 + cbs),
                (lvoid*)((char*)Bs0 + chunk), 16, 0, 0);
            __builtin_amdgcn_global_load_lds(
                (gvoid*)(Bbase + (size_t)r * strideB + (size_t)(K + k0) * 2 + cbs),
                (lvoid*)((char*)Bs1 + chunk), 16, 0, 0);
        }
        __syncthreads();

        // product 1: Ahi * Bhi
#pragma unroll
        for (int kk = 0; kk < 2; ++kk) {
            short8 af[4], bfr[4];
#pragma unroll
            for (int m = 0; m < 4; ++m) {
                const int row = wr + m * 16 + lr;
                const int cbb = (kk * 64 + kbB) ^ ((row & 7) << 4);
                af[m] = *(const short8*)((const char*)As + row * 128 + cbb);
            }
#pragma unroll
            for (int n = 0; n < 4; ++n) {
                const int row = wc + n * 16 + lr;
                const int cbb = (kk * 64 + kbB) ^ ((row & 7) << 4);
                bfr[n] = *(const short8*)((const char*)Bs0 + row * 128 + cbb);
            }
#pragma unroll
            for (int m = 0; m < 4; ++m)
#pragma unroll
                for (int n = 0; n < 4; ++n)
                    acc[m][n] = __builtin_amdgcn_mfma_f32_16x16x32_bf16(af[m], bfr[n], acc[m][n], 0, 0, 0);
        }
        // product 2: Ahi * Blo
#pragma unroll
        for (int kk = 0; kk < 2; ++kk) {
            short8 af[4], bfr[4];
#pragma unroll
            for (int m = 0; m < 4; ++m) {
                const int row = wr + m * 16 + lr;
                const int cbb = (kk * 64 + kbB) ^ ((row & 7) << 4);
                af[m] = *(const short8*)((const char*)As + row * 128 + cbb);
            }
#pragma unroll
            for (int n = 0; n < 4; ++n) {
                const int row = wc + n * 16 + lr;
                const int cbb = (kk * 64 + kbB) ^ ((row & 7) << 4);
                bfr[n] = *(const short8*)((const char*)Bs1 + row * 128 + cbb);
            }
#pragma unroll
            for (int m = 0; m < 4; ++m)
#pragma unroll
                for (int n = 0; n < 4; ++n)
                    acc[m][n] = __builtin_amdgcn_mfma_f32_16x16x32_bf16(af[m], bfr[n], acc[m][n], 0, 0, 0);
        }

        // ---- phase 2: stage Alo over As ----
        __syncthreads();
#pragma unroll
        for (int i = 0; i < 4; ++i) {
            const int chunk = (i * 4 + wid) * 1024;
            const int off = chunk + lane * 16;
            const int r = off >> 7;
            const int cb = off & 127;
            const int cbs = cb ^ ((r & 7) << 4);
            const char* asrc;
            if (MODE == 2) {
                asrc = (const char*)Alo + (size_t)arow[i] * strideA + (size_t)k0 * 2 + cbs;
            } else {
                asrc = (const char*)Alo + (size_t)(baseRow + row0 + r) * strideA + (size_t)k0 * 2 + cbs;
            }
            __builtin_amdgcn_global_load_lds((gvoid*)asrc, (lvoid*)((char*)As + chunk), 16, 0, 0);
        }
        __syncthreads();

        // product 3: Alo * Bhi
#pragma unroll
        for (int kk = 0; kk < 2; ++kk) {
            short8 af[4], bfr[4];
#pragma unroll
            for (int m = 0; m < 4; ++m) {
                const int row = wr + m * 16 + lr;
                const int cbb = (kk * 64 + kbB) ^ ((row & 7) << 4);
                af[m] = *(const short8*)((const char*)As + row * 128 + cbb);
            }
#pragma unroll
            for (int n = 0; n < 4; ++n) {
                const int row = wc + n * 16 + lr;
                const int cbb = (kk * 64 + kbB) ^ ((row & 7) << 4);
                bfr[n] = *(const short8*)((const char*)Bs0 + row * 128 + cbb);
            }
#pragma unroll
            for (int m = 0; m < 4; ++m)
#pragma unroll
                for (int n = 0; n < 4; ++n)
                    acc[m][n] = __builtin_amdgcn_mfma_f32_16x16x32_bf16(af[m], bfr[n], acc[m][n], 0, 0, 0);
        }
    }

    const int rb4 = (lane >> 4) * 4;
#pragma unroll
    for (int m = 0; m < 4; ++m) {
#pragma unroll
        for (int n = 0; n < 4; ++n) {
#pragma unroll
            for (int r = 0; r < 4; ++r) {
                const int row = row0 + wr + m * 16 + rb4 + r;
                const int col = col0 + wc + n * 16 + lr;
                if (row >= Mv) continue;
                const float v = acc[m][n][r];
                if (MODE == 0) {
                    outf[(size_t)row * N + col] = v + bias[col];
                } else if (MODE == 1) {
                    outf[(size_t)row * N + col] += v + bias[col];
                } else if (MODE == 2) {
                    const float g = gate[rmap[row] * 4 + e];
                    const float y = g * gelu_f(v + bias[e * N + col]);
                    __hip_bfloat16 h, l; split2(y, h, l);
                    outh[((size_t)(baseRow + row)) * ldOut + col] = h;
                    outh[((size_t)(baseRow + row)) * ldOut + N + col] = l;
                } else if (MODE == 3) {
                    outf[outStride * blockIdx.y + ((size_t)(baseRow + row)) * N + col] = v;
                } else if (MODE == 4) {
                    const int bi = row / 196;
                    const int pp = row - bi * 196;
                    outf[((size_t)(bi * 197 + 1 + pp)) * N + col] = v + bias[col] + aux[(size_t)(1 + pp) * N + col];
                }
            }
        }
    }
}

// ---------------- LayerNorm with hi/lo split output (initial + final use) ----------------
__global__ void ln_split(const float* __restrict__ x, const float* __restrict__ w,
                         const float* __restrict__ b, __hip_bfloat16* __restrict__ hi,
                         __hip_bfloat16* __restrict__ lo, float* __restrict__ out32,
                         int nrows, int in_stride)
{
    const int row = blockIdx.x * 4 + (threadIdx.x >> 6);
    const int lane = threadIdx.x & 63;
    if (row >= nrows) return;
    const float4 v = ((const float4*)(x + (size_t)row * in_stride))[lane];
    float s = v.x + v.y + v.z + v.w;
#pragma unroll
    for (int o = 32; o; o >>= 1) s += __shfl_xor(s, o);
    const float mean = s * (1.f / 256.f);
    const float dx = v.x - mean, dy = v.y - mean, dz = v.z - mean, dw = v.w - mean;
    float q = dx * dx + dy * dy + dz * dz + dw * dw;
#pragma unroll
    for (int o = 32; o; o >>= 1) q += __shfl_xor(q, o);
    const float inv = rsqrtf(q * (1.f / 256.f) + 1e-5f);
    const int c = lane * 4;
    const float4 wv = ((const float4*)w)[lane];
    const float4 bv = ((const float4*)b)[lane];
    float y[4];
    y[0] = dx * inv * wv.x + bv.x;
    y[1] = dy * inv * wv.y + bv.y;
    y[2] = dz * inv * wv.z + bv.z;
    y[3] = dw * inv * wv.w + bv.w;
    if (hi) {
#pragma unroll
        for (int j = 0; j < 4; ++j) {
            __hip_bfloat16 h, l; split2(y[j], h, l);
            hi[(size_t)row * 256 + c + j] = h;
            lo[(size_t)row * 256 + c + j] = l;
        }
    }
    if (out32) {
        ((float4*)(out32 + (size_t)row * 256))[lane] = make_float4(y[0], y[1], y[2], y[3]);
    }
}

// ---------------- fused LN2 + router (+ zero cnt) ----------------
__global__ void ln2_router(const float* __restrict__ x, const float* __restrict__ w,
                           const float* __restrict__ b, __hip_bfloat16* __restrict__ hi,
                           __hip_bfloat16* __restrict__ lo,
                           const float* __restrict__ rw, const float* __restrict__ rb,
                           float* __restrict__ gate, int* __restrict__ top2,
                           int* __restrict__ cnt, int T)
{
    if (blockIdx.x == 0 && threadIdx.x < 4) cnt[threadIdx.x] = 0;
    const int row = blockIdx.x * 4 + (threadIdx.x >> 6);
    const int lane = threadIdx.x & 63;
    if (row >= T) return;
    const float4 v = ((const float4*)(x + (size_t)row * 256))[lane];
    float s = v.x + v.y + v.z + v.w;
#pragma unroll
    for (int o = 32; o; o >>= 1) s += __shfl_xor(s, o);
    const float mean = s * (1.f / 256.f);
    const float dx = v.x - mean, dy = v.y - mean, dz = v.z - mean, dw = v.w - mean;
    float q = dx * dx + dy * dy + dz * dz + dw * dw;
#pragma unroll
    for (int o = 32; o; o >>= 1) q += __shfl_xor(q, o);
    const float inv = rsqrtf(q * (1.f / 256.f) + 1e-5f);
    const int c = lane * 4;
    const float4 wv = ((const float4*)w)[lane];
    const float4 bv = ((const float4*)b)[lane];
    float y[4];
    y[0] = dx * inv * wv.x + bv.x;
    y[1] = dy * inv * wv.y + bv.y;
    y[2] = dz * inv * wv.z + bv.z;
    y[3] = dw * inv * wv.w + bv.w;
#pragma unroll
    for (int jj = 0; jj < 4; ++jj) {
        __hip_bfloat16 h, l; split2(y[jj], h, l);
        hi[(size_t)row * 256 + c + jj] = h;
        lo[(size_t)row * 256 + c + jj] = l;
    }
    float a0 = 0, a1 = 0, a2 = 0, a3 = 0;
#pragma unroll
    for (int jj = 0; jj < 4; ++jj) {
        const float xs = y[jj];
        const float4 wr4 = ((const float4*)rw)[lane * 4 + jj];
        a0 += xs * wr4.x; a1 += xs * wr4.y; a2 += xs * wr4.z; a3 += xs * wr4.w;
    }
#pragma unroll
    for (int o = 32; o; o >>= 1) {
        a0 += __shfl_xor(a0, o); a1 += __shfl_xor(a1, o);
        a2 += __shfl_xor(a2, o); a3 += __shfl_xor(a3, o);
    }
    if (lane == 0) {
        float l[4] = {a0 + rb[0], a1 + rb[1], a2 + rb[2], a3 + rb[3]};
        const float m = fmaxf(fmaxf(l[0], l[1]), fmaxf(l[2], l[3]));
        float pr[4]; float sm = 0.f;
#pragma unroll
        for (int n = 0; n < 4; ++n) { pr[n] = expf(l[n] - m); sm += pr[n]; }
#pragma unroll
        for (int n = 0; n < 4; ++n) pr[n] /= sm;
        int i0 = 0;
        for (int n = 1; n < 4; ++n) if (pr[n] > pr[i0]) i0 = n;
        int i1 = -1;
        for (int n = 0; n < 4; ++n) { if (n == i0) continue; if (i1 < 0 || pr[n] > pr[i1]) i1 = n; }
        const float wsum = pr[i0] + pr[i1];
        float g[4] = {0.f, 0.f, 0.f, 0.f};
        g[i0] = pr[i0] / wsum; g[i1] = pr[i1] / wsum;
        ((float4*)gate)[row] = make_float4(g[0], g[1], g[2], g[3]);
        top2[row] = i0 | (i1 << 4);
    }
}

// ---------------- build per-expert token lists + per-token positions ----------------
__global__ void build_list(const int* __restrict__ top2, int* __restrict__ cnt,
                           int* __restrict__ list, int* __restrict__ poslist, int T)
{
    const int t = blockIdx.x * 256 + threadIdx.x;
    const int lane = threadIdx.x & 63;
    int i0 = -1, i1 = -1;
    if (t < T) { const int v = top2[t]; i0 = v & 15; i1 = v >> 4; }
    const unsigned long long lt = (lane == 63) ? ~0ull >> 1 : (1ull << lane) - 1;
#pragma unroll
    for (int e = 0; e < 4; ++e) {
#pragma unroll
        for (int s = 0; s < 2; ++s) {
            const int sel = s ? i1 : i0;
            const unsigned long long m = __ballot(sel == e);
            if (m) {
                const int leader = __ffsll((long long)m) - 1;
                int base = 0;
                if (lane == leader) base = atomicAdd(&cnt[e], __popcll(m));
                base = __shfl(base, leader);
                if (sel == e) {
                    const int p = base + __popcll(m & lt);
                    list[e * T_TOK + p] = t;
                    poslist[2 * t + s] = p;
                }
            }
        }
    }
}

// ---------------- fused MoE combine (2 split-K slices) + next-layer LN1 ----------------
__global__ void combine_ln(const float* __restrict__ ebuf, size_t sliceOff,
                           const int* __restrict__ top2,
                           const int* __restrict__ poslist, const int* __restrict__ cnt,
                           const float* __restrict__ gate, const float* __restrict__ e_b2,
                           float* __restrict__ z,
                           const float* __restrict__ lnw, const float* __restrict__ lnb,
                           __hip_bfloat16* __restrict__ hi, __hip_bfloat16* __restrict__ lo,
                           int T)
{
    const int t = blockIdx.x * 4 + (threadIdx.x >> 6);
    const int lane = threadIdx.x & 63;
    if (t >= T) return;
    const int tp = top2[t];
    const int e0 = tp & 15, e1 = tp >> 4;
    const size_t g0 = (size_t)base_of(cnt, e0) + poslist[2 * t];
    const size_t g1 = (size_t)base_of(cnt, e1) + poslist[2 * t + 1];
    const float4 a  = ((const float4*)(ebuf + g0 * 256))[lane];
    const float4 bq = ((const float4*)(ebuf + g1 * 256))[lane];
    const float4 a2 = ((const float4*)(ebuf + sliceOff + g0 * 256))[lane];
    const float4 b2q = ((const float4*)(ebuf + sliceOff + g1 * 256))[lane];
    const float4 gw = ((const float4*)gate)[t];
    const float4 b0 = ((const float4*)(e_b2 + 0 * 256))[lane];
    const float4 b1 = ((const float4*)(e_b2 + 1 * 256))[lane];
    const float4 b2 = ((const float4*)(e_b2 + 2 * 256))[lane];
    const float4 b3 = ((const float4*)(e_b2 + 3 * 256))[lane];
    float4* zp = (float4*)(z + (size_t)t * 256);
    float4 acc = zp[lane];
    acc.x += (a.x + a2.x) + (bq.x + b2q.x) + gw.x * b0.x + gw.y * b1.x + gw.z * b2.x + gw.w * b3.x;
    acc.y += (a.y + a2.y) + (bq.y + b2q.y) + gw.x * b0.y + gw.y * b1.y + gw.z * b2.y + gw.w * b3.y;
    acc.z += (a.z + a2.z) + (bq.z + b2q.z) + gw.x * b0.z + gw.y * b1.z + gw.z * b2.z + gw.w * b3.z;
    acc.w += (a.w + a2.w) + (bq.w + b2q.w) + gw.x * b0.w + gw.y * b1.w + gw.z * b2.w + gw.w * b3.w;
    zp[lane] = acc;
    if (lnw) {
        float s = acc.x + acc.y + acc.z + acc.w;
#pragma unroll
        for (int o = 32; o; o >>= 1) s += __shfl_xor(s, o);
        const float mean = s * (1.f / 256.f);
        const float dx = acc.x - mean, dy = acc.y - mean, dz = acc.z - mean, dw = acc.w - mean;
        float q = dx * dx + dy * dy + dz * dz + dw * dw;
#pragma unroll
        for (int o = 32; o; o >>= 1) q += __shfl_xor(q, o);
        const float inv = rsqrtf(q * (1.f / 256.f) + 1e-5f);
        const int c = lane * 4;
        const float4 wv = ((const float4*)lnw)[lane];
        const float4 bv = ((const float4*)lnb)[lane];
        float y[4];
        y[0] = dx * inv * wv.x + bv.x;
        y[1] = dy * inv * wv.y + bv.y;
        y[2] = dz * inv * wv.z + bv.z;
        y[3] = dw * inv * wv.w + bv.w;
#pragma unroll
        for (int jj = 0; jj < 4; ++jj) {
            __hip_bfloat16 h, l; split2(y[jj], h, l);
            hi[(size_t)t * 256 + c + jj] = h;
            lo[(size_t)t * 256 + c + jj] = l;
        }
    }
}

// ---------------- attention v6: MFMA flash-attention, full split-bf16 ----------------
#define VSTR 232
__global__ __launch_bounds__(256, 1)
void attn_v6(const float* __restrict__ qkv, __hip_bfloat16* __restrict__ ctxhi,
             __hip_bfloat16* __restrict__ ctxlo)
{
    __shared__ short Qhf[13 * 512], Qlf[13 * 512], Khf[13 * 512], Klf[13 * 512];
    __shared__ short Vth[32 * VSTR], Vtl[32 * VSTR];
    __shared__ short Pfh[4 * 512], Pfl[4 * 512];
    const int b = blockIdx.x >> 3;
    const int h = blockIdx.x & 7;
    const int tid = threadIdx.x, lane = tid & 63, wid = tid >> 6;
    const int g = lane >> 4;
    const size_t base = ((size_t)b * S_TOK) * 768 + h * 32;

    for (int idx = tid; idx < 208 * 8; idx += 256) {
        const int s = idx >> 3, c4 = idx & 7;
        float4 qv = make_float4(0.f, 0.f, 0.f, 0.f);
        float4 kv = make_float4(0.f, 0.f, 0.f, 0.f);
        if (s < S_TOK) {
            const float* row = qkv + base + (size_t)s * 768;
            qv = *(const float4*)(row + c4 * 4);
            kv = *(const float4*)(row + 256 + c4 * 4);
        }
        short4v qh, ql, kh, kl;
#pragma unroll
        for (int j = 0; j < 4; ++j) {
            __hip_bfloat16 hh, ll;
            split2((&qv.x)[j], hh, ll);
            qh[j] = *reinterpret_cast<short*>(&hh); ql[j] = *reinterpret_cast<short*>(&ll);
            split2((&kv.x)[j], hh, ll);
            kh[j] = *reinterpret_cast<short*>(&hh); kl[j] = *reinterpret_cast<short*>(&ll);
        }
        const int off = (s >> 4) * 512 + ((s & 15) + ((c4 >> 1) << 4)) * 8 + (c4 & 1) * 4;
        *(short4v*)&Qhf[off] = qh; *(short4v*)&Qlf[off] = ql;
        *(short4v*)&Khf[off] = kh; *(short4v*)&Klf[off] = kl;
    }
    for (int idx = tid; idx < S_TOK * 8; idx += 256) {
        const int s = idx >> 3, c4 = idx & 7;
        const float4 vv = *(const float4*)(qkv + base + (size_t)s * 768 + 512 + c4 * 4);
#pragma unroll
        for (int j = 0; j < 4; ++j) {
            __hip_bfloat16 hh, ll; split2((&vv.x)[j], hh, ll);
            Vth[(c4 * 4 + j) * VSTR + s] = *reinterpret_cast<short*>(&hh);
            Vtl[(c4 * 4 + j) * VSTR + s] = *reinterpret_cast<short*>(&ll);
        }
    }
    for (int idx = tid; idx < 32 * (VSTR - S_TOK); idx += 256) {
        const int d = idx / (VSTR - S_TOK), s = S_TOK + idx % (VSTR - S_TOK);
        Vth[d * VSTR + s] = 0;
        Vtl[d * VSTR + s] = 0;
    }
    __syncthreads();

    const float scale = 0.17677669529663687f;  // 1/sqrt(32)
    for (int qt = wid; qt < 13; qt += 4) {
        const short8 qh  = *(const short8*)&Qhf[qt * 512 + lane * 8];
        const short8 qlo = *(const short8*)&Qlf[qt * 512 + lane * 8];
        f32x4 o0 = (f32x4){0.f, 0.f, 0.f, 0.f};
        f32x4 o1 = (f32x4){0.f, 0.f, 0.f, 0.f};
        float lsum = 0.f;
        for (int kp = 0; kp < 7; ++kp) {
#pragma unroll
            for (int half = 0; half < 2; ++half) {
                const int kt = kp * 2 + half;
                short4v pkh = (short4v){0, 0, 0, 0};
                short4v pkl = (short4v){0, 0, 0, 0};
                if (kt < 13) {
                    const short8 kh = *(const short8*)&Khf[kt * 512 + lane * 8];
                    const short8 kl = *(const short8*)&Klf[kt * 512 + lane * 8];
                    f32x4 st = (f32x4){0.f, 0.f, 0.f, 0.f};
                    st = __builtin_amdgcn_mfma_f32_16x16x32_bf16(kh, qh,  st, 0, 0, 0);
                    st = __builtin_amdgcn_mfma_f32_16x16x32_bf16(kl, qh,  st, 0, 0, 0);
                    st = __builtin_amdgcn_mfma_f32_16x16x32_bf16(kh, qlo, st, 0, 0, 0);
#pragma unroll
                    for (int r = 0; r < 4; ++r) {
                        const int sg = kt * 16 + g * 4 + r;
                        const float e = (sg < S_TOK) ? __expf(st[r] * scale) : 0.f;
                        lsum += e;
                        __hip_bfloat16 hh, ll; split2(e, hh, ll);
                        pkh[r] = *reinterpret_cast<short*>(&hh);
                        pkl[r] = *reinterpret_cast<short*>(&ll);
                    }
                }
                const int slb = half * 16 + g * 4;
                const int lp = (lane & 15) + ((slb >> 3) << 4);
                *(short4v*)&Pfh[wid * 512 + lp * 8 + (slb & 4)] = pkh;
                *(short4v*)&Pfl[wid * 512 + lp * 8 + (slb & 4)] = pkl;
            }
            asm volatile("s_waitcnt lgkmcnt(0)" ::: "memory");
            __builtin_amdgcn_sched_barrier(0);
            const short8 pfh = *(const short8*)&Pfh[wid * 512 + lane * 8];
            const short8 pfl = *(const short8*)&Pfl[wid * 512 + lane * 8];
            const int vo = kp * 32 + g * 8;
            const short8 vah = *(const short8*)&Vth[(lane & 15) * VSTR + vo];
            const short8 valo = *(const short8*)&Vtl[(lane & 15) * VSTR + vo];
            const short8 vbh = *(const short8*)&Vth[((lane & 15) + 16) * VSTR + vo];
            const short8 vblo = *(const short8*)&Vtl[((lane & 15) + 16) * VSTR + vo];
            o0 = __builtin_amdgcn_mfma_f32_16x16x32_bf16(vah,  pfh, o0, 0, 0, 0);
            o0 = __builtin_amdgcn_mfma_f32_16x16x32_bf16(vah,  pfl, o0, 0, 0, 0);
            o0 = __builtin_amdgcn_mfma_f32_16x16x32_bf16(valo, pfh, o0, 0, 0, 0);
            o1 = __builtin_amdgcn_mfma_f32_16x16x32_bf16(vbh,  pfh, o1, 0, 0, 0);
            o1 = __builtin_amdgcn_mfma_f32_16x16x32_bf16(vbh,  pfl, o1, 0, 0, 0);
            o1 = __builtin_amdgcn_mfma_f32_16x16x32_bf16(vblo, pfh, o1, 0, 0, 0);
        }
        float lr = lsum;
        lr += __shfl_xor(lr, 16);
        lr += __shfl_xor(lr, 32);
        const int q = qt * 16 + (lane & 15);
        if (q < S_TOK) {
            const float inv = 1.f / lr;
            const size_t orow = ((size_t)b * S_TOK + q) * 256 + h * 32;
#pragma unroll
            for (int r = 0; r < 4; ++r) {
                __hip_bfloat16 hh, ll;
                split2(o0[r] * inv, hh, ll);
                ctxhi[orow + g * 4 + r] = hh;
                ctxlo[orow + g * 4 + r] = ll;
                split2(o1[r] * inv, hh, ll);
                ctxhi[orow + 16 + g * 4 + r] = hh;
                ctxlo[orow + 16 + g * 4 + r] = ll;
            }
        }
    }
}

// ---------------- weight prep: [K][N] fp32 -> [N][2K] bf16 [Bhi|Blo] ----------------
__global__ void transpose_split(const float* __restrict__ in, short* __restrict__ out,
                                int K, int N, size_t inBatch, size_t outBatch)
{
    __shared__ float tile[32][33];
    const int n0 = blockIdx.x * 32, k0 = blockIdx.y * 32;
    const float* src = in + blockIdx.z * inBatch;
    __hip_bfloat16* dst = (__hip_bfloat16*)out + blockIdx.z * outBatch;
    const int tx = threadIdx.x & 31, ty = threadIdx.x >> 5;
#pragma unroll
    for (int i = 0; i < 32; i += 8)
        tile[ty + i][tx] = src[(size_t)(k0 + ty + i) * N + (n0 + tx)];
    __syncthreads();
    const int ld2 = 2 * K;
#pragma unroll
    for (int i = 0; i < 32; i += 8) {
        const float v = tile[tx][ty + i];
        __hip_bfloat16 h, l; split2(v, h, l);
        const int n = n0 + ty + i, k = k0 + tx;
        dst[(size_t)n * ld2 + k] = h;
        dst[(size_t)n * ld2 + K + k] = l;
    }
}

// in [N][K] fp32 (already B^T layout) -> out [N][2K]: [hi | lo]
__global__ void split_rows(const float* __restrict__ in, short* __restrict__ out, int N, int K)
{
    const int idx = blockIdx.x * 256 + threadIdx.x;
    if (idx >= N * K) return;
    const int n = idx / K, k = idx - n * K;
    __hip_bfloat16 h, l; split2(in[idx], h, l);
    __hip_bfloat16* dst = (__hip_bfloat16*)out;
    dst[(size_t)n * 2 * K + k] = h;
    dst[(size_t)n * 2 * K + K + k] = l;
}

__global__ void im2col_split(const float* __restrict__ x, short* __restrict__ out)
{
    const int t = blockIdx.x;                 // 0..12543
    const int b = t / 196, p = t - b * 196;
    const int py = p / 14, px = p - py * 14;
    __hip_bfloat16* dst = (__hip_bfloat16*)out;
    for (int c_ = threadIdx.x; c_ < 768; c_ += 256) {
        const int c = c_ >> 8, r = c_ & 255;
        const int ky = r >> 4, kx = r & 15;
        const float v = x[(((size_t)b * 3 + c) * 224 + (py * 16 + ky)) * 224 + (px * 16 + kx)];
        __hip_bfloat16 h, l; split2(v, h, l);
        dst[(size_t)t * 1536 + c_] = h;
        dst[(size_t)t * 1536 + 768 + c_] = l;
    }
}

__global__ void cls_init(const float* __restrict__ cls_tok, const float* __restrict__ pos,
                         float* __restrict__ z)
{
    const int b = blockIdx.x, e = threadIdx.x;
    z[((size_t)b * S_TOK) * 256 + e] = cls_tok[e] + pos[e];
}

__global__ void head1_kernel(const float* __restrict__ clsln, const float* __restrict__ w,
                             const float* __restrict__ bias, float* __restrict__ hbuf)
{
    __shared__ float xs[256];
    const int b = blockIdx.x, n = threadIdx.x;
    xs[n] = clsln[b * 256 + n];
    __syncthreads();
    float acc = bias[n];
    for (int k = 0; k < 256; ++k) acc += xs[k] * w[k * 256 + n];
    hbuf[b * 256 + n] = gelu_f(acc);
}

__global__ void head2_kernel(const float* __restrict__ hbuf, const float* __restrict__ w,
                             const float* __restrict__ bias, float* __restrict__ out)
{
    __shared__ float xs[256];
    const int b = blockIdx.x, t = threadIdx.x;
    xs[t] = hbuf[b * 256 + t];
    __syncthreads();
    if (t < 38) {
        float acc = bias[t];
        for (int k = 0; k < 256; ++k) acc += xs[k] * w[k * 38 + t];
        out[b * 38 + t] = acc;
    }
}

// ---------------- launch ----------------
extern "C" void kernel_launch(void* const* d_in, const int* in_sizes, int n_in,
                              void* d_out, int out_size, void* d_ws, size_t ws_size,
                              hipStream_t stream)
{
    const float* x       = (const float*)d_in[0];
    const float* conv_w  = (const float*)d_in[1];
    const float* conv_b  = (const float*)d_in[2];
    const float* cls_tok = (const float*)d_in[3];
    const float* pos     = (const float*)d_in[4];
    const float* ln1_w   = (const float*)d_in[5];
    const float* ln1_b   = (const float*)d_in[6];
    const float* qkv_w   = (const float*)d_in[7];
    const float* qkv_b   = (const float*)d_in[8];
    const float* out_w   = (const float*)d_in[9];
    const float* out_b   = (const float*)d_in[10];
    const float* ln2_w   = (const float*)d_in[11];
    const float* ln2_b   = (const float*)d_in[12];
    const float* rw      = (const float*)d_in[13];
    const float* rb      = (const float*)d_in[14];
    const float* e_w1    = (const float*)d_in[15];
    const float* e_b1    = (const float*)d_in[16];
    const float* e_w2    = (const float*)d_in[17];
    const float* e_b2    = (const float*)d_in[18];
    const float* norm_w  = (const float*)d_in[19];
    const float* norm_b  = (const float*)d_in[20];
    const float* h1_w    = (const float*)d_in[21];
    const float* h1_b    = (const float*)d_in[22];
    const float* h2_w    = (const float*)d_in[23];
    const float* h2_b    = (const float*)d_in[24];
    float* outp = (float*)d_out;

    char* ws = (char*)d_ws;
    size_t off = 0;
    auto alloc = [&](size_t bytes) -> char* {
        char* p = ws + off;
        off += (bytes + 255) & ~(size_t)255;
        return p;
    };

    float* zbuf    = (float*)alloc((size_t)T_TOK * 256 * 4);
    short* xfhi    = (short*)alloc((size_t)MPAD * 256 * 2);
    short* xflo    = (short*)alloc((size_t)MPAD * 256 * 2);
    float* qkvbuf  = (float*)alloc((size_t)T_TOK * 768 * 4);
    float* ebuf    = qkvbuf;   // slice-0 alias (25.9MB <= 38.7MB; qkv dead during moe2)
    float* ebuf1   = (float*)alloc((size_t)(2 * T_TOK) * 256 * 4);  // slice-1 partials
    short* ctxhi   = (short*)alloc((size_t)MPAD * 256 * 2);
    short* ctxlo   = (short*)alloc((size_t)MPAD * 256 * 2);
    float* gate    = (float*)alloc((size_t)T_TOK * 4 * 4);
    short* he_full = (short*)alloc((size_t)(2 * MPAD) * 2048 * 2); // all-expert compact acts [hi|lo]
    short* patches = he_full;  // alias: [12544][1536] hi|lo, dead after patch-embed GEMM
    // all-layer hoisted weight buffers ([N][2K] = [Bhi|Blo])
    short* qkvWall = (short*)alloc((size_t)DEPTH_L * 768 * 512 * 2);      // [L][768][512]
    short* woutAll = (short*)alloc((size_t)DEPTH_L * 256 * 512 * 2);      // [L][256][512]
    short* w1All   = (short*)alloc((size_t)DEPTH_L * 4 * 1024 * 512 * 2); // [L][4][1024][512]
    short* w2All   = (short*)alloc((size_t)DEPTH_L * 4 * 256 * 2048 * 2); // [L][4][256][2048]
    short* convext = (short*)alloc((size_t)256 * 1536 * 2);               // [256][1536]
    float* clsln   = (float*)alloc((size_t)64 * 256 * 4);
    float* hbuf    = (float*)alloc((size_t)64 * 256 * 4);
    int*   elist   = (int*)alloc((size_t)4 * T_TOK * 4);       // per-expert token lists
    int*   poslist = (int*)alloc((size_t)2 * T_TOK * 4);       // per-token in-expert positions
    int*   ecnt    = (int*)alloc(256);                         // 4 counters
    int*   top2    = (int*)alloc((size_t)T_TOK * 4);           // packed top-2 ids

    const size_t sliceOff = (size_t)(ebuf1 - ebuf);            // element offset slice0->slice1

    // ---- hoisted weight prep: ALL layers in 4 batched dispatches ----
    transpose_split<<<dim3(24, 8, DEPTH_L), 256, 0, stream>>>(qkv_w, qkvWall,
                                                              256, 768, 196608, 393216);
    transpose_split<<<dim3(8, 8, DEPTH_L), 256, 0, stream>>>(out_w, woutAll,
                                                             256, 256, 65536, 131072);
    transpose_split<<<dim3(32, 8, 4 * DEPTH_L), 256, 0, stream>>>(e_w1, w1All,
                                                                  256, 1024, 262144, 524288);
    transpose_split<<<dim3(8, 32, 4 * DEPTH_L), 256, 0, stream>>>(e_w2, w2All,
                                                                  1024, 256, 262144, 524288);
    split_rows<<<768, 256, 0, stream>>>(conv_w, convext, 256, 768);

    // ---- patch embedding (split precision) ----
    im2col_split<<<12544, 256, 0, stream>>>(x, patches);
    gemm3<4><<<208, 256, 0, stream>>>(patches, patches + 768, 1536, convext,
                                      zbuf, nullptr, 0, conv_b, nullptr, pos,
                                      nullptr, nullptr, 12544, 256, 768, 98,
                                      768, 0);
    cls_init<<<64, 256, 0, stream>>>(cls_tok, pos, zbuf);

    // ---- LN1 for layer 0 (subsequent layers get it fused into combine_ln) ----
    ln_split<<<3152, 256, 0, stream>>>(zbuf, ln1_w, ln1_b,
                                       (__hip_bfloat16*)xfhi, (__hip_bfloat16*)xflo,
                                       nullptr, T_TOK, 256);

    // ---- transformer layers ----
    for (int i = 0; i < DEPTH_L; ++i) {
        // attention block (xfhi/xflo already hold LN1 output)
        gemm3<0><<<624, 256, 0, stream>>>(xfhi, xflo, 256, qkvWall + (size_t)i * 393216,
                                          qkvbuf, nullptr, 0, qkv_b + i * 768,
                                          nullptr, nullptr, nullptr, nullptr,
                                          T_TOK, 768, 256, 99, 256, 0);
        attn_v6<<<512, 256, 0, stream>>>(qkvbuf, (__hip_bfloat16*)ctxhi, (__hip_bfloat16*)ctxlo);
        gemm3<1><<<208, 256, 0, stream>>>(ctxhi, ctxlo, 256, woutAll + (size_t)i * 131072,
                                          zbuf, nullptr, 0, out_b + i * 256,
                                          nullptr, nullptr, nullptr, nullptr,
                                          T_TOK, 256, 256, 99, 256, 0);
        // MoE block (fused LN2+router, top-2 sparse, merged dispatches, atomic-free)
        ln2_router<<<3152, 256, 0, stream>>>(zbuf, ln2_w + i * 256, ln2_b + i * 256,
                                             (__hip_bfloat16*)xfhi, (__hip_bfloat16*)xflo,
                                             rw + i * 1024, rb + i * 4, gate, top2, ecnt, T_TOK);
        build_list<<<50, 256, 0, stream>>>(top2, ecnt, elist, poslist, T_TOK);
        gemm3<2><<<dim3(832, 1, 4), 256, 0, stream>>>(xfhi, xflo, 256,
                                                      w1All + (size_t)i * 4 * 524288,
                                                      nullptr, (__hip_bfloat16*)he_full, 2048,
                                                      e_b1 + (size_t)i * 4096, gate, nullptr,
                                                      elist, ecnt, T_TOK, 1024, 256, 99,
                                                      256, 0);
        gemm3<3><<<dim3(208, 2, 4), 256, 0, stream>>>(he_full, he_full + 1024, 2048,
                                                      w2All + (size_t)i * 4 * 524288,
                                                      ebuf, nullptr, 0, nullptr, nullptr, nullptr,
                                                      nullptr, ecnt, T_TOK, 256, 1024, 99,
                                                      512, sliceOff);
        if (i < DEPTH_L - 1) {
            combine_ln<<<3152, 256, 0, stream>>>(ebuf, sliceOff, top2, poslist, ecnt, gate,
                                                 e_b2 + (size_t)i * 1024, zbuf,
                                                 ln1_w + (i + 1) * 256, ln1_b + (i + 1) * 256,
                                                 (__hip_bfloat16*)xfhi, (__hip_bfloat16*)xflo,
                                                 T_TOK);
        } else {
            combine_ln<<<3152, 256, 0, stream>>>(ebuf, sliceOff, top2, poslist, ecnt, gate,
                                                 e_b2 + (size_t)i * 1024, zbuf,
                                                 nullptr, nullptr, nullptr, nullptr, T_TOK);
        }
    }

    // ---- head ----
    ln_split<<<16, 256, 0, stream>>>(zbuf, norm_w, norm_b, nullptr, nullptr, clsln, 64, S_TOK * 256);
    head1_kernel<<<64, 256, 0, stream>>>(clsln, h1_w, h1_b, hbuf);
    head2_kernel<<<64, 256, 0, stream>>>(hbuf, h2_w, h2_b, outp);

    (void)in_sizes; (void)n_in; (void)out_size; (void)ws_size;
}

// Round 21
// 1360.772 us; speedup vs baseline: 1.0746x; 1.0746x over previous
//
#include <hip/hip_runtime.h>
#include <hip/hip_bf16.h>

#define T_TOK 12608      // 64*197
#define MPAD  12672      // 99*128
#define S_TOK 197
#define DEPTH_L 4

typedef __attribute__((ext_vector_type(8))) short short8;
typedef __attribute__((ext_vector_type(4))) short short4v;
typedef __attribute__((ext_vector_type(4))) float f32x4;

using gvoid = __attribute__((address_space(1))) const void;
using lvoid = __attribute__((address_space(3))) void;

__device__ __forceinline__ float gelu_f(float x) {
    return 0.5f * x * (1.f + erff(x * 0.70710678118654752440f));
}

__device__ __forceinline__ void split2(float v, __hip_bfloat16& h, __hip_bfloat16& l) {
    h = __float2bfloat16(v);
    l = __float2bfloat16(v - __bfloat162float(h));
}

// prefix base for expert e from counts (inline; no calc_base kernel)
__device__ __forceinline__ int base_of(const int* __restrict__ cnt, int e) {
    int b = 0;
#pragma unroll
    for (int k = 0; k < 3; ++k) if (e > k) b += cnt[k];
    return b;
}

// ---------------- split-bf16 3-product GEMM, 128x128 tile, BK=64 ----------------
// K-extension over 3K steps (regions of width K):
//   region 0: Ahi * Bhi   region 1: Alo * Bhi   region 2: Ahi * Blo
// B stored as Bext[N][2K] = [Bhi | Blo]; region->B offset is INDEXED
// (0->ka, 1->ka, 2->K+ka) instead of materializing a duplicated Bhi.
// Same product order as the proven r18 kernel => bitwise-identical results;
// -33% weight-buffer bytes and -33% B HBM fetch, same LDS/VGPR/occupancy.
// XCD-interleaved swizzle: xcd=x&7, j=x>>3, p=(j%13)*8+xcd, c=j/13.
// LDS 2x16KB=32KB -> 4 blocks/CU; rule-21 XOR swizzle (col ^ ((row&7)<<4)).
// launch_bounds(256,4): PROVEN floor. (256,8)/(256,5) spill acc (r13/r16);
// 3-buffer variant (r19) -> 48KB LDS + 108 VGPR -> occupancy 17%, +30% time.
// Split-K (MODE 3): blockIdx.y slice covers extended-k in [y*kChunk,(y+1)*kChunk);
// slice y plain-stores to outf + y*outStride; combine sums slices.
// MODE 0: outf = v + bias            (qkv)
// MODE 1: outf += v + bias           (attn out proj, residual)
// MODE 2: sparse moe1 (rowmap gather; gate*gelu; hi/lo out)
// MODE 3: sparse moe2 (compact A; plain store to slice buffer)
// MODE 4: patch embed scatter (+pos)
template<int MODE>
__global__ __launch_bounds__(256, 4)
void gemm3(const short* __restrict__ Ahi, const short* __restrict__ Alo, int ldA,
           const short* __restrict__ Bext,
           float* __restrict__ outf, __hip_bfloat16* __restrict__ outh, int ldOut,
           const float* __restrict__ bias, const float* __restrict__ gate,
           const float* __restrict__ aux,
           const int* __restrict__ rowmap, const int* __restrict__ cntp,
           int Mvalid, int N, int K, int npanels, int kChunk, size_t outStride)
{
    __shared__ short As[128 * 64];
    __shared__ short Bs[128 * 64];
    const int tid  = threadIdx.x;
    const int wid  = tid >> 6;
    const int lane = tid & 63;

    const int xcd = blockIdx.x & 7;
    const int j   = blockIdx.x >> 3;
    const int p   = (j % 13) * 8 + xcd;
    const int c   = j / 13;
    if (p >= npanels) return;            // uniform exit
    const int row0 = p * 128;
    const int col0 = c * 128;

    const int wr = (wid >> 1) * 64;
    const int wc = (wid & 1) * 64;
    const int e  = (MODE == 2 || MODE == 3) ? blockIdx.z : 0;

    int Mv = Mvalid;
    int baseRow = 0;
    const int* rmap = nullptr;
    if (MODE == 2 || MODE == 3) {
        Mv = cntp[e];
        if (row0 >= Mv) return;          // uniform early-exit (before any barrier)
        baseRow = base_of(cntp, e);
        if (MODE == 2) rmap = rowmap + e * T_TOK;
    }

    // MODE 2: row-indirect A staging; lane's tile row per i: (i*4+wid)*8+(lane>>3).
    int arow[4];
    if (MODE == 2) {
#pragma unroll
        for (int i = 0; i < 4; ++i) {
            int gr = row0 + (i * 4 + wid) * 8 + (lane >> 3);
            if (gr > Mv - 1) gr = Mv - 1;
            arow[i] = rmap[gr];
        }
    }

    f32x4 acc[4][4];
#pragma unroll
    for (int m = 0; m < 4; ++m)
#pragma unroll
        for (int n = 0; n < 4; ++n) acc[m][n] = (f32x4){0.f, 0.f, 0.f, 0.f};

    const int ld3 = 3 * K;
    const size_t strideA = (size_t)ldA * 2;
    const size_t strideB = (size_t)(2 * K) * 2;   // B rows are [Bhi|Blo] (2K shorts)
    const char* Bbase = (const char*)Bext + ((size_t)e * N + col0) * strideB;

    const int kBeg = blockIdx.y * kChunk;
    int kEnd = kBeg + kChunk; if (kEnd > ld3) kEnd = ld3;

    for (int k0 = kBeg; k0 < kEnd; k0 += 64) {
        const int regio = (k0 >= K) + (k0 >= 2 * K);
        const short* Asrc = (regio == 1) ? Alo : Ahi;
        const int ka = k0 - regio * K;
        const int kb = (regio == 2) ? (K + ka) : ka;   // region->B column
        __syncthreads();
#pragma unroll
        for (int i = 0; i < 4; ++i) {
            const int chunk = (i * 4 + wid) * 1024;          // wave-uniform LDS dest (bytes)
            const int off = chunk + lane * 16;
            const int r = off >> 7;                          // 128B per tile row
            const int cb = off & 127;
            const int cbs = cb ^ ((r & 7) << 4);             // inverse-swizzled source col
            const char* asrc;
            if (MODE == 2) {
                asrc = (const char*)Asrc + (size_t)arow[i] * strideA + (size_t)ka * 2 + cbs;
            } else {
                asrc = (const char*)Asrc + (size_t)(baseRow + row0 + r) * strideA + (size_t)ka * 2 + cbs;
            }
            __builtin_amdgcn_global_load_lds((gvoid*)asrc, (lvoid*)((char*)As + chunk), 16, 0, 0);
            __builtin_amdgcn_global_load_lds(
                (gvoid*)(Bbase + (size_t)r * strideB + (size_t)kb * 2 + cbs),
                (lvoid*)((char*)Bs + chunk), 16, 0, 0);
        }
        __syncthreads();

        const int lr = lane & 15;
        const int kbB = (lane >> 4) * 16;                    // frag byte offset within 64B
#pragma unroll
        for (int kk = 0; kk < 2; ++kk) {
            short8 af[4], bfr[4];
#pragma unroll
            for (int m = 0; m < 4; ++m) {
                const int row = wr + m * 16 + lr;
                const int cbb = (kk * 64 + kbB) ^ ((row & 7) << 4);
                af[m] = *(const short8*)((const char*)As + row * 128 + cbb);
            }
#pragma unroll
            for (int n = 0; n < 4; ++n) {
                const int row = wc + n * 16 + lr;
                const int cbb = (kk * 64 + kbB) ^ ((row & 7) << 4);
                bfr[n] = *(const short8*)((const char*)Bs + row * 128 + cbb);
            }
#pragma unroll
            for (int m = 0; m < 4; ++m)
#pragma unroll
                for (int n = 0; n < 4; ++n)
                    acc[m][n] = __builtin_amdgcn_mfma_f32_16x16x32_bf16(af[m], bfr[n], acc[m][n], 0, 0, 0);
        }
    }

    const int lr = lane & 15;
    const int rb4 = (lane >> 4) * 4;
#pragma unroll
    for (int m = 0; m < 4; ++m) {
#pragma unroll
        for (int n = 0; n < 4; ++n) {
#pragma unroll
            for (int r = 0; r < 4; ++r) {
                const int row = row0 + wr + m * 16 + rb4 + r;
                const int col = col0 + wc + n * 16 + lr;
                if (row >= Mv) continue;
                const float v = acc[m][n][r];
                if (MODE == 0) {
                    outf[(size_t)row * N + col] = v + bias[col];
                } else if (MODE == 1) {
                    outf[(size_t)row * N + col] += v + bias[col];
                } else if (MODE == 2) {
                    const float g = gate[rmap[row] * 4 + e];
                    const float y = g * gelu_f(v + bias[e * N + col]);
                    __hip_bfloat16 h, l; split2(y, h, l);
                    outh[((size_t)(baseRow + row)) * ldOut + col] = h;
                    outh[((size_t)(baseRow + row)) * ldOut + N + col] = l;
                } else if (MODE == 3) {
                    outf[outStride * blockIdx.y + ((size_t)(baseRow + row)) * N + col] = v;
                } else if (MODE == 4) {
                    const int bi = row / 196;
                    const int pp = row - bi * 196;
                    outf[((size_t)(bi * 197 + 1 + pp)) * N + col] = v + bias[col] + aux[(size_t)(1 + pp) * N + col];
                }
            }
        }
    }
}

// ---------------- LayerNorm with hi/lo split output (initial + final use) ----------------
__global__ void ln_split(const float* __restrict__ x, const float* __restrict__ w,
                         const float* __restrict__ b, __hip_bfloat16* __restrict__ hi,
                         __hip_bfloat16* __restrict__ lo, float* __restrict__ out32,
                         int nrows, int in_stride)
{
    const int row = blockIdx.x * 4 + (threadIdx.x >> 6);
    const int lane = threadIdx.x & 63;
    if (row >= nrows) return;
    const float4 v = ((const float4*)(x + (size_t)row * in_stride))[lane];
    float s = v.x + v.y + v.z + v.w;
#pragma unroll
    for (int o = 32; o; o >>= 1) s += __shfl_xor(s, o);
    const float mean = s * (1.f / 256.f);
    const float dx = v.x - mean, dy = v.y - mean, dz = v.z - mean, dw = v.w - mean;
    float q = dx * dx + dy * dy + dz * dz + dw * dw;
#pragma unroll
    for (int o = 32; o; o >>= 1) q += __shfl_xor(q, o);
    const float inv = rsqrtf(q * (1.f / 256.f) + 1e-5f);
    const int c = lane * 4;
    const float4 wv = ((const float4*)w)[lane];
    const float4 bv = ((const float4*)b)[lane];
    float y[4];
    y[0] = dx * inv * wv.x + bv.x;
    y[1] = dy * inv * wv.y + bv.y;
    y[2] = dz * inv * wv.z + bv.z;
    y[3] = dw * inv * wv.w + bv.w;
    if (hi) {
#pragma unroll
        for (int j = 0; j < 4; ++j) {
            __hip_bfloat16 h, l; split2(y[j], h, l);
            hi[(size_t)row * 256 + c + j] = h;
            lo[(size_t)row * 256 + c + j] = l;
        }
    }
    if (out32) {
        ((float4*)(out32 + (size_t)row * 256))[lane] = make_float4(y[0], y[1], y[2], y[3]);
    }
}

// ---------------- fused LN2 + router (+ zero cnt) ----------------
__global__ void ln2_router(const float* __restrict__ x, const float* __restrict__ w,
                           const float* __restrict__ b, __hip_bfloat16* __restrict__ hi,
                           __hip_bfloat16* __restrict__ lo,
                           const float* __restrict__ rw, const float* __restrict__ rb,
                           float* __restrict__ gate, int* __restrict__ top2,
                           int* __restrict__ cnt, int T)
{
    if (blockIdx.x == 0 && threadIdx.x < 4) cnt[threadIdx.x] = 0;
    const int row = blockIdx.x * 4 + (threadIdx.x >> 6);
    const int lane = threadIdx.x & 63;
    if (row >= T) return;
    const float4 v = ((const float4*)(x + (size_t)row * 256))[lane];
    float s = v.x + v.y + v.z + v.w;
#pragma unroll
    for (int o = 32; o; o >>= 1) s += __shfl_xor(s, o);
    const float mean = s * (1.f / 256.f);
    const float dx = v.x - mean, dy = v.y - mean, dz = v.z - mean, dw = v.w - mean;
    float q = dx * dx + dy * dy + dz * dz + dw * dw;
#pragma unroll
    for (int o = 32; o; o >>= 1) q += __shfl_xor(q, o);
    const float inv = rsqrtf(q * (1.f / 256.f) + 1e-5f);
    const int c = lane * 4;
    const float4 wv = ((const float4*)w)[lane];
    const float4 bv = ((const float4*)b)[lane];
    float y[4];
    y[0] = dx * inv * wv.x + bv.x;
    y[1] = dy * inv * wv.y + bv.y;
    y[2] = dz * inv * wv.z + bv.z;
    y[3] = dw * inv * wv.w + bv.w;
#pragma unroll
    for (int jj = 0; jj < 4; ++jj) {
        __hip_bfloat16 h, l; split2(y[jj], h, l);
        hi[(size_t)row * 256 + c + jj] = h;
        lo[(size_t)row * 256 + c + jj] = l;
    }
    float a0 = 0, a1 = 0, a2 = 0, a3 = 0;
#pragma unroll
    for (int jj = 0; jj < 4; ++jj) {
        const float xs = y[jj];
        const float4 wr4 = ((const float4*)rw)[lane * 4 + jj];
        a0 += xs * wr4.x; a1 += xs * wr4.y; a2 += xs * wr4.z; a3 += xs * wr4.w;
    }
#pragma unroll
    for (int o = 32; o; o >>= 1) {
        a0 += __shfl_xor(a0, o); a1 += __shfl_xor(a1, o);
        a2 += __shfl_xor(a2, o); a3 += __shfl_xor(a3, o);
    }
    if (lane == 0) {
        float l[4] = {a0 + rb[0], a1 + rb[1], a2 + rb[2], a3 + rb[3]};
        const float m = fmaxf(fmaxf(l[0], l[1]), fmaxf(l[2], l[3]));
        float pr[4]; float sm = 0.f;
#pragma unroll
        for (int n = 0; n < 4; ++n) { pr[n] = expf(l[n] - m); sm += pr[n]; }
#pragma unroll
        for (int n = 0; n < 4; ++n) pr[n] /= sm;
        int i0 = 0;
        for (int n = 1; n < 4; ++n) if (pr[n] > pr[i0]) i0 = n;
        int i1 = -1;
        for (int n = 0; n < 4; ++n) { if (n == i0) continue; if (i1 < 0 || pr[n] > pr[i1]) i1 = n; }
        const float wsum = pr[i0] + pr[i1];
        float g[4] = {0.f, 0.f, 0.f, 0.f};
        g[i0] = pr[i0] / wsum; g[i1] = pr[i1] / wsum;
        ((float4*)gate)[row] = make_float4(g[0], g[1], g[2], g[3]);
        top2[row] = i0 | (i1 << 4);
    }
}

// ---------------- build per-expert token lists + per-token positions ----------------
__global__ void build_list(const int* __restrict__ top2, int* __restrict__ cnt,
                           int* __restrict__ list, int* __restrict__ poslist, int T)
{
    const int t = blockIdx.x * 256 + threadIdx.x;
    const int lane = threadIdx.x & 63;
    int i0 = -1, i1 = -1;
    if (t < T) { const int v = top2[t]; i0 = v & 15; i1 = v >> 4; }
    const unsigned long long lt = (lane == 63) ? ~0ull >> 1 : (1ull << lane) - 1;
#pragma unroll
    for (int e = 0; e < 4; ++e) {
#pragma unroll
        for (int s = 0; s < 2; ++s) {
            const int sel = s ? i1 : i0;
            const unsigned long long m = __ballot(sel == e);
            if (m) {
                const int leader = __ffsll((long long)m) - 1;
                int base = 0;
                if (lane == leader) base = atomicAdd(&cnt[e], __popcll(m));
                base = __shfl(base, leader);
                if (sel == e) {
                    const int p = base + __popcll(m & lt);
                    list[e * T_TOK + p] = t;
                    poslist[2 * t + s] = p;
                }
            }
        }
    }
}

// ---------------- fused MoE combine (2 split-K slices) + next-layer LN1 ----------------
__global__ void combine_ln(const float* __restrict__ ebuf, size_t sliceOff,
                           const int* __restrict__ top2,
                           const int* __restrict__ poslist, const int* __restrict__ cnt,
                           const float* __restrict__ gate, const float* __restrict__ e_b2,
                           float* __restrict__ z,
                           const float* __restrict__ lnw, const float* __restrict__ lnb,
                           __hip_bfloat16* __restrict__ hi, __hip_bfloat16* __restrict__ lo,
                           int T)
{
    const int t = blockIdx.x * 4 + (threadIdx.x >> 6);
    const int lane = threadIdx.x & 63;
    if (t >= T) return;
    const int tp = top2[t];
    const int e0 = tp & 15, e1 = tp >> 4;
    const size_t g0 = (size_t)base_of(cnt, e0) + poslist[2 * t];
    const size_t g1 = (size_t)base_of(cnt, e1) + poslist[2 * t + 1];
    const float4 a  = ((const float4*)(ebuf + g0 * 256))[lane];
    const float4 bq = ((const float4*)(ebuf + g1 * 256))[lane];
    const float4 a2 = ((const float4*)(ebuf + sliceOff + g0 * 256))[lane];
    const float4 b2q = ((const float4*)(ebuf + sliceOff + g1 * 256))[lane];
    const float4 gw = ((const float4*)gate)[t];
    const float4 b0 = ((const float4*)(e_b2 + 0 * 256))[lane];
    const float4 b1 = ((const float4*)(e_b2 + 1 * 256))[lane];
    const float4 b2 = ((const float4*)(e_b2 + 2 * 256))[lane];
    const float4 b3 = ((const float4*)(e_b2 + 3 * 256))[lane];
    float4* zp = (float4*)(z + (size_t)t * 256);
    float4 acc = zp[lane];
    acc.x += (a.x + a2.x) + (bq.x + b2q.x) + gw.x * b0.x + gw.y * b1.x + gw.z * b2.x + gw.w * b3.x;
    acc.y += (a.y + a2.y) + (bq.y + b2q.y) + gw.x * b0.y + gw.y * b1.y + gw.z * b2.y + gw.w * b3.y;
    acc.z += (a.z + a2.z) + (bq.z + b2q.z) + gw.x * b0.z + gw.y * b1.z + gw.z * b2.z + gw.w * b3.z;
    acc.w += (a.w + a2.w) + (bq.w + b2q.w) + gw.x * b0.w + gw.y * b1.w + gw.z * b2.w + gw.w * b3.w;
    zp[lane] = acc;
    if (lnw) {
        float s = acc.x + acc.y + acc.z + acc.w;
#pragma unroll
        for (int o = 32; o; o >>= 1) s += __shfl_xor(s, o);
        const float mean = s * (1.f / 256.f);
        const float dx = acc.x - mean, dy = acc.y - mean, dz = acc.z - mean, dw = acc.w - mean;
        float q = dx * dx + dy * dy + dz * dz + dw * dw;
#pragma unroll
        for (int o = 32; o; o >>= 1) q += __shfl_xor(q, o);
        const float inv = rsqrtf(q * (1.f / 256.f) + 1e-5f);
        const int c = lane * 4;
        const float4 wv = ((const float4*)lnw)[lane];
        const float4 bv = ((const float4*)lnb)[lane];
        float y[4];
        y[0] = dx * inv * wv.x + bv.x;
        y[1] = dy * inv * wv.y + bv.y;
        y[2] = dz * inv * wv.z + bv.z;
        y[3] = dw * inv * wv.w + bv.w;
#pragma unroll
        for (int jj = 0; jj < 4; ++jj) {
            __hip_bfloat16 h, l; split2(y[jj], h, l);
            hi[(size_t)t * 256 + c + jj] = h;
            lo[(size_t)t * 256 + c + jj] = l;
        }
    }
}

// ---------------- attention v6: MFMA flash-attention, full split-bf16 ----------------
#define VSTR 232
__global__ __launch_bounds__(256, 1)
void attn_v6(const float* __restrict__ qkv, __hip_bfloat16* __restrict__ ctxhi,
             __hip_bfloat16* __restrict__ ctxlo)
{
    __shared__ short Qhf[13 * 512], Qlf[13 * 512], Khf[13 * 512], Klf[13 * 512];
    __shared__ short Vth[32 * VSTR], Vtl[32 * VSTR];
    __shared__ short Pfh[4 * 512], Pfl[4 * 512];
    const int b = blockIdx.x >> 3;
    const int h = blockIdx.x & 7;
    const int tid = threadIdx.x, lane = tid & 63, wid = tid >> 6;
    const int g = lane >> 4;
    const size_t base = ((size_t)b * S_TOK) * 768 + h * 32;

    for (int idx = tid; idx < 208 * 8; idx += 256) {
        const int s = idx >> 3, c4 = idx & 7;
        float4 qv = make_float4(0.f, 0.f, 0.f, 0.f);
        float4 kv = make_float4(0.f, 0.f, 0.f, 0.f);
        if (s < S_TOK) {
            const float* row = qkv + base + (size_t)s * 768;
            qv = *(const float4*)(row + c4 * 4);
            kv = *(const float4*)(row + 256 + c4 * 4);
        }
        short4v qh, ql, kh, kl;
#pragma unroll
        for (int j = 0; j < 4; ++j) {
            __hip_bfloat16 hh, ll;
            split2((&qv.x)[j], hh, ll);
            qh[j] = *reinterpret_cast<short*>(&hh); ql[j] = *reinterpret_cast<short*>(&ll);
            split2((&kv.x)[j], hh, ll);
            kh[j] = *reinterpret_cast<short*>(&hh); kl[j] = *reinterpret_cast<short*>(&ll);
        }
        const int off = (s >> 4) * 512 + ((s & 15) + ((c4 >> 1) << 4)) * 8 + (c4 & 1) * 4;
        *(short4v*)&Qhf[off] = qh; *(short4v*)&Qlf[off] = ql;
        *(short4v*)&Khf[off] = kh; *(short4v*)&Klf[off] = kl;
    }
    for (int idx = tid; idx < S_TOK * 8; idx += 256) {
        const int s = idx >> 3, c4 = idx & 7;
        const float4 vv = *(const float4*)(qkv + base + (size_t)s * 768 + 512 + c4 * 4);
#pragma unroll
        for (int j = 0; j < 4; ++j) {
            __hip_bfloat16 hh, ll; split2((&vv.x)[j], hh, ll);
            Vth[(c4 * 4 + j) * VSTR + s] = *reinterpret_cast<short*>(&hh);
            Vtl[(c4 * 4 + j) * VSTR + s] = *reinterpret_cast<short*>(&ll);
        }
    }
    for (int idx = tid; idx < 32 * (VSTR - S_TOK); idx += 256) {
        const int d = idx / (VSTR - S_TOK), s = S_TOK + idx % (VSTR - S_TOK);
        Vth[d * VSTR + s] = 0;
        Vtl[d * VSTR + s] = 0;
    }
    __syncthreads();

    const float scale = 0.17677669529663687f;  // 1/sqrt(32)
    for (int qt = wid; qt < 13; qt += 4) {
        const short8 qh  = *(const short8*)&Qhf[qt * 512 + lane * 8];
        const short8 qlo = *(const short8*)&Qlf[qt * 512 + lane * 8];
        f32x4 o0 = (f32x4){0.f, 0.f, 0.f, 0.f};
        f32x4 o1 = (f32x4){0.f, 0.f, 0.f, 0.f};
        float lsum = 0.f;
        for (int kp = 0; kp < 7; ++kp) {
#pragma unroll
            for (int half = 0; half < 2; ++half) {
                const int kt = kp * 2 + half;
                short4v pkh = (short4v){0, 0, 0, 0};
                short4v pkl = (short4v){0, 0, 0, 0};
                if (kt < 13) {
                    const short8 kh = *(const short8*)&Khf[kt * 512 + lane * 8];
                    const short8 kl = *(const short8*)&Klf[kt * 512 + lane * 8];
                    f32x4 st = (f32x4){0.f, 0.f, 0.f, 0.f};
                    st = __builtin_amdgcn_mfma_f32_16x16x32_bf16(kh, qh,  st, 0, 0, 0);
                    st = __builtin_amdgcn_mfma_f32_16x16x32_bf16(kl, qh,  st, 0, 0, 0);
                    st = __builtin_amdgcn_mfma_f32_16x16x32_bf16(kh, qlo, st, 0, 0, 0);
#pragma unroll
                    for (int r = 0; r < 4; ++r) {
                        const int sg = kt * 16 + g * 4 + r;
                        const float e = (sg < S_TOK) ? __expf(st[r] * scale) : 0.f;
                        lsum += e;
                        __hip_bfloat16 hh, ll; split2(e, hh, ll);
                        pkh[r] = *reinterpret_cast<short*>(&hh);
                        pkl[r] = *reinterpret_cast<short*>(&ll);
                    }
                }
                const int slb = half * 16 + g * 4;
                const int lp = (lane & 15) + ((slb >> 3) << 4);
                *(short4v*)&Pfh[wid * 512 + lp * 8 + (slb & 4)] = pkh;
                *(short4v*)&Pfl[wid * 512 + lp * 8 + (slb & 4)] = pkl;
            }
            asm volatile("s_waitcnt lgkmcnt(0)" ::: "memory");
            __builtin_amdgcn_sched_barrier(0);
            const short8 pfh = *(const short8*)&Pfh[wid * 512 + lane * 8];
            const short8 pfl = *(const short8*)&Pfl[wid * 512 + lane * 8];
            const int vo = kp * 32 + g * 8;
            const short8 vah = *(const short8*)&Vth[(lane & 15) * VSTR + vo];
            const short8 valo = *(const short8*)&Vtl[(lane & 15) * VSTR + vo];
            const short8 vbh = *(const short8*)&Vth[((lane & 15) + 16) * VSTR + vo];
            const short8 vblo = *(const short8*)&Vtl[((lane & 15) + 16) * VSTR + vo];
            o0 = __builtin_amdgcn_mfma_f32_16x16x32_bf16(vah,  pfh, o0, 0, 0, 0);
            o0 = __builtin_amdgcn_mfma_f32_16x16x32_bf16(vah,  pfl, o0, 0, 0, 0);
            o0 = __builtin_amdgcn_mfma_f32_16x16x32_bf16(valo, pfh, o0, 0, 0, 0);
            o1 = __builtin_amdgcn_mfma_f32_16x16x32_bf16(vbh,  pfh, o1, 0, 0, 0);
            o1 = __builtin_amdgcn_mfma_f32_16x16x32_bf16(vbh,  pfl, o1, 0, 0, 0);
            o1 = __builtin_amdgcn_mfma_f32_16x16x32_bf16(vblo, pfh, o1, 0, 0, 0);
        }
        float lr = lsum;
        lr += __shfl_xor(lr, 16);
        lr += __shfl_xor(lr, 32);
        const int q = qt * 16 + (lane & 15);
        if (q < S_TOK) {
            const float inv = 1.f / lr;
            const size_t orow = ((size_t)b * S_TOK + q) * 256 + h * 32;
#pragma unroll
            for (int r = 0; r < 4; ++r) {
                __hip_bfloat16 hh, ll;
                split2(o0[r] * inv, hh, ll);
                ctxhi[orow + g * 4 + r] = hh;
                ctxlo[orow + g * 4 + r] = ll;
                split2(o1[r] * inv, hh, ll);
                ctxhi[orow + 16 + g * 4 + r] = hh;
                ctxlo[orow + 16 + g * 4 + r] = ll;
            }
        }
    }
}

// ---------------- weight prep: [K][N] fp32 -> [N][2K] bf16 [Bhi|Blo] ----------------
__global__ void transpose_split(const float* __restrict__ in, short* __restrict__ out,
                                int K, int N, size_t inBatch, size_t outBatch)
{
    __shared__ float tile[32][33];
    const int n0 = blockIdx.x * 32, k0 = blockIdx.y * 32;
    const float* src = in + blockIdx.z * inBatch;
    __hip_bfloat16* dst = (__hip_bfloat16*)out + blockIdx.z * outBatch;
    const int tx = threadIdx.x & 31, ty = threadIdx.x >> 5;
#pragma unroll
    for (int i = 0; i < 32; i += 8)
        tile[ty + i][tx] = src[(size_t)(k0 + ty + i) * N + (n0 + tx)];
    __syncthreads();
    const int ld2 = 2 * K;
#pragma unroll
    for (int i = 0; i < 32; i += 8) {
        const float v = tile[tx][ty + i];
        __hip_bfloat16 h, l; split2(v, h, l);
        const int n = n0 + ty + i, k = k0 + tx;
        dst[(size_t)n * ld2 + k] = h;
        dst[(size_t)n * ld2 + K + k] = l;
    }
}

// in [N][K] fp32 (already B^T layout) -> out [N][2K]: [hi | lo]
__global__ void split_rows(const float* __restrict__ in, short* __restrict__ out, int N, int K)
{
    const int idx = blockIdx.x * 256 + threadIdx.x;
    if (idx >= N * K) return;
    const int n = idx / K, k = idx - n * K;
    __hip_bfloat16 h, l; split2(in[idx], h, l);
    __hip_bfloat16* dst = (__hip_bfloat16*)out;
    dst[(size_t)n * 2 * K + k] = h;
    dst[(size_t)n * 2 * K + K + k] = l;
}

__global__ void im2col_split(const float* __restrict__ x, short* __restrict__ out)
{
    const int t = blockIdx.x;                 // 0..12543
    const int b = t / 196, p = t - b * 196;
    const int py = p / 14, px = p - py * 14;
    __hip_bfloat16* dst = (__hip_bfloat16*)out;
    for (int c_ = threadIdx.x; c_ < 768; c_ += 256) {
        const int c = c_ >> 8, r = c_ & 255;
        const int ky = r >> 4, kx = r & 15;
        const float v = x[(((size_t)b * 3 + c) * 224 + (py * 16 + ky)) * 224 + (px * 16 + kx)];
        __hip_bfloat16 h, l; split2(v, h, l);
        dst[(size_t)t * 1536 + c_] = h;
        dst[(size_t)t * 1536 + 768 + c_] = l;
    }
}

__global__ void cls_init(const float* __restrict__ cls_tok, const float* __restrict__ pos,
                         float* __restrict__ z)
{
    const int b = blockIdx.x, e = threadIdx.x;
    z[((size_t)b * S_TOK) * 256 + e] = cls_tok[e] + pos[e];
}

__global__ void head1_kernel(const float* __restrict__ clsln, const float* __restrict__ w,
                             const float* __restrict__ bias, float* __restrict__ hbuf)
{
    __shared__ float xs[256];
    const int b = blockIdx.x, n = threadIdx.x;
    xs[n] = clsln[b * 256 + n];
    __syncthreads();
    float acc = bias[n];
    for (int k = 0; k < 256; ++k) acc += xs[k] * w[k * 256 + n];
    hbuf[b * 256 + n] = gelu_f(acc);
}

__global__ void head2_kernel(const float* __restrict__ hbuf, const float* __restrict__ w,
                             const float* __restrict__ bias, float* __restrict__ out)
{
    __shared__ float xs[256];
    const int b = blockIdx.x, t = threadIdx.x;
    xs[t] = hbuf[b * 256 + t];
    __syncthreads();
    if (t < 38) {
        float acc = bias[t];
        for (int k = 0; k < 256; ++k) acc += xs[k] * w[k * 38 + t];
        out[b * 38 + t] = acc;
    }
}

// ---------------- launch ----------------
extern "C" void kernel_launch(void* const* d_in, const int* in_sizes, int n_in,
                              void* d_out, int out_size, void* d_ws, size_t ws_size,
                              hipStream_t stream)
{
    const float* x       = (const float*)d_in[0];
    const float* conv_w  = (const float*)d_in[1];
    const float* conv_b  = (const float*)d_in[2];
    const float* cls_tok = (const float*)d_in[3];
    const float* pos     = (const float*)d_in[4];
    const float* ln1_w   = (const float*)d_in[5];
    const float* ln1_b   = (const float*)d_in[6];
    const float* qkv_w   = (const float*)d_in[7];
    const float* qkv_b   = (const float*)d_in[8];
    const float* out_w   = (const float*)d_in[9];
    const float* out_b   = (const float*)d_in[10];
    const float* ln2_w   = (const float*)d_in[11];
    const float* ln2_b   = (const float*)d_in[12];
    const float* rw      = (const float*)d_in[13];
    const float* rb      = (const float*)d_in[14];
    const float* e_w1    = (const float*)d_in[15];
    const float* e_b1    = (const float*)d_in[16];
    const float* e_w2    = (const float*)d_in[17];
    const float* e_b2    = (const float*)d_in[18];
    const float* norm_w  = (const float*)d_in[19];
    const float* norm_b  = (const float*)d_in[20];
    const float* h1_w    = (const float*)d_in[21];
    const float* h1_b    = (const float*)d_in[22];
    const float* h2_w    = (const float*)d_in[23];
    const float* h2_b    = (const float*)d_in[24];
    float* outp = (float*)d_out;

    char* ws = (char*)d_ws;
    size_t off = 0;
    auto alloc = [&](size_t bytes) -> char* {
        char* p = ws + off;
        off += (bytes + 255) & ~(size_t)255;
        return p;
    };

    float* zbuf    = (float*)alloc((size_t)T_TOK * 256 * 4);
    short* xfhi    = (short*)alloc((size_t)MPAD * 256 * 2);
    short* xflo    = (short*)alloc((size_t)MPAD * 256 * 2);
    float* qkvbuf  = (float*)alloc((size_t)T_TOK * 768 * 4);
    float* ebuf    = qkvbuf;   // slice-0 alias (25.9MB <= 38.7MB; qkv dead during moe2)
    float* ebuf1   = (float*)alloc((size_t)(2 * T_TOK) * 256 * 4);  // slice-1 partials
    short* ctxhi   = (short*)alloc((size_t)MPAD * 256 * 2);
    short* ctxlo   = (short*)alloc((size_t)MPAD * 256 * 2);
    float* gate    = (float*)alloc((size_t)T_TOK * 4 * 4);
    short* he_full = (short*)alloc((size_t)(2 * MPAD) * 2048 * 2); // all-expert compact acts [hi|lo]
    short* patches = he_full;  // alias: [12544][1536] hi|lo, dead after patch-embed GEMM
    // all-layer hoisted weight buffers ([N][2K] = [Bhi|Blo])
    short* qkvWall = (short*)alloc((size_t)DEPTH_L * 768 * 512 * 2);      // [L][768][512]
    short* woutAll = (short*)alloc((size_t)DEPTH_L * 256 * 512 * 2);      // [L][256][512]
    short* w1All   = (short*)alloc((size_t)DEPTH_L * 4 * 1024 * 512 * 2); // [L][4][1024][512]
    short* w2All   = (short*)alloc((size_t)DEPTH_L * 4 * 256 * 2048 * 2); // [L][4][256][2048]
    short* convext = (short*)alloc((size_t)256 * 1536 * 2);               // [256][1536]
    float* clsln   = (float*)alloc((size_t)64 * 256 * 4);
    float* hbuf    = (float*)alloc((size_t)64 * 256 * 4);
    int*   elist   = (int*)alloc((size_t)4 * T_TOK * 4);       // per-expert token lists
    int*   poslist = (int*)alloc((size_t)2 * T_TOK * 4);       // per-token in-expert positions
    int*   ecnt    = (int*)alloc(256);                         // 4 counters
    int*   top2    = (int*)alloc((size_t)T_TOK * 4);           // packed top-2 ids

    const size_t sliceOff = (size_t)(ebuf1 - ebuf);            // element offset slice0->slice1

    // ---- hoisted weight prep: ALL layers in 4 batched dispatches ----
    transpose_split<<<dim3(24, 8, DEPTH_L), 256, 0, stream>>>(qkv_w, qkvWall,
                                                              256, 768, 196608, 393216);
    transpose_split<<<dim3(8, 8, DEPTH_L), 256, 0, stream>>>(out_w, woutAll,
                                                             256, 256, 65536, 131072);
    transpose_split<<<dim3(32, 8, 4 * DEPTH_L), 256, 0, stream>>>(e_w1, w1All,
                                                                  256, 1024, 262144, 524288);
    transpose_split<<<dim3(8, 32, 4 * DEPTH_L), 256, 0, stream>>>(e_w2, w2All,
                                                                  1024, 256, 262144, 524288);
    split_rows<<<768, 256, 0, stream>>>(conv_w, convext, 256, 768);

    // ---- patch embedding (split precision) ----
    im2col_split<<<12544, 256, 0, stream>>>(x, patches);
    gemm3<4><<<208, 256, 0, stream>>>(patches, patches + 768, 1536, convext,
                                      zbuf, nullptr, 0, conv_b, nullptr, pos,
                                      nullptr, nullptr, 12544, 256, 768, 98,
                                      3 * 768, 0);
    cls_init<<<64, 256, 0, stream>>>(cls_tok, pos, zbuf);

    // ---- LN1 for layer 0 (subsequent layers get it fused into combine_ln) ----
    ln_split<<<3152, 256, 0, stream>>>(zbuf, ln1_w, ln1_b,
                                       (__hip_bfloat16*)xfhi, (__hip_bfloat16*)xflo,
                                       nullptr, T_TOK, 256);

    // ---- transformer layers ----
    for (int i = 0; i < DEPTH_L; ++i) {
        // attention block (xfhi/xflo already hold LN1 output)
        gemm3<0><<<624, 256, 0, stream>>>(xfhi, xflo, 256, qkvWall + (size_t)i * 393216,
                                          qkvbuf, nullptr, 0, qkv_b + i * 768,
                                          nullptr, nullptr, nullptr, nullptr,
                                          T_TOK, 768, 256, 99, 3 * 256, 0);
        attn_v6<<<512, 256, 0, stream>>>(qkvbuf, (__hip_bfloat16*)ctxhi, (__hip_bfloat16*)ctxlo);
        gemm3<1><<<208, 256, 0, stream>>>(ctxhi, ctxlo, 256, woutAll + (size_t)i * 131072,
                                          zbuf, nullptr, 0, out_b + i * 256,
                                          nullptr, nullptr, nullptr, nullptr,
                                          T_TOK, 256, 256, 99, 3 * 256, 0);
        // MoE block (fused LN2+router, top-2 sparse, merged dispatches, atomic-free)
        ln2_router<<<3152, 256, 0, stream>>>(zbuf, ln2_w + i * 256, ln2_b + i * 256,
                                             (__hip_bfloat16*)xfhi, (__hip_bfloat16*)xflo,
                                             rw + i * 1024, rb + i * 4, gate, top2, ecnt, T_TOK);
        build_list<<<50, 256, 0, stream>>>(top2, ecnt, elist, poslist, T_TOK);
        gemm3<2><<<dim3(832, 1, 4), 256, 0, stream>>>(xfhi, xflo, 256,
                                                      w1All + (size_t)i * 4 * 524288,
                                                      nullptr, (__hip_bfloat16*)he_full, 2048,
                                                      e_b1 + (size_t)i * 4096, gate, nullptr,
                                                      elist, ecnt, T_TOK, 1024, 256, 99,
                                                      3 * 256, 0);
        gemm3<3><<<dim3(208, 2, 4), 256, 0, stream>>>(he_full, he_full + 1024, 2048,
                                                      w2All + (size_t)i * 4 * 524288,
                                                      ebuf, nullptr, 0, nullptr, nullptr, nullptr,
                                                      nullptr, ecnt, T_TOK, 256, 1024, 99,
                                                      1536, sliceOff);
        if (i < DEPTH_L - 1) {
            combine_ln<<<3152, 256, 0, stream>>>(ebuf, sliceOff, top2, poslist, ecnt, gate,
                                                 e_b2 + (size_t)i * 1024, zbuf,
                                                 ln1_w + (i + 1) * 256, ln1_b + (i + 1) * 256,
                                                 (__hip_bfloat16*)xfhi, (__hip_bfloat16*)xflo,
                                                 T_TOK);
        } else {
            combine_ln<<<3152, 256, 0, stream>>>(ebuf, sliceOff, top2, poslist, ecnt, gate,
                                                 e_b2 + (size_t)i * 1024, zbuf,
                                                 nullptr, nullptr, nullptr, nullptr, T_TOK);
        }
    }

    // ---- head ----
    ln_split<<<16, 256, 0, stream>>>(zbuf, norm_w, norm_b, nullptr, nullptr, clsln, 64, S_TOK * 256);
    head1_kernel<<<64, 256, 0, stream>>>(clsln, h1_w, h1_b, hbuf);
    head2_kernel<<<64, 256, 0, stream>>>(hbuf, h2_w, h2_b, outp);

    (void)in_sizes; (void)n_in; (void)out_size; (void)ws_size;
}